// Round 11
// baseline (55.661 us; speedup 1.0000x reference)
//
#include <hip/hip_runtime.h>

// Problem constants (from reference)
constexpr int COLS    = 8;
constexpr int BATCH   = 8192;
constexpr int D       = 128;
constexpr int NUM_EMB = 12;
constexpr int NPAIRS  = 28;

typedef float floatx4 __attribute__((ext_vector_type(4)));

__device__ __forceinline__ floatx4 ld4(const float* p) {
    return *reinterpret_cast<const floatx4*>(p);
}
__device__ __forceinline__ void st4(float* p, floatx4 v) {
    *reinterpret_cast<floatx4*>(p) = v;
}
__device__ __forceinline__ float softplus01(float x) {
    return 0.01f * ((x > 15.0f) ? x : log1pf(expf(x)));
}
__device__ __forceinline__ float dot4(floatx4 a, floatx4 b) {
    return fmaf(a.x, b.x, fmaf(a.y, b.y, fmaf(a.z, b.z, a.w * b.w)));
}

// Block = 512 threads = 8 waves; each 32-lane half-wave owns one batch row
// (16 rows/block, grid = 512). LDS weights (57 KB) -> 2 blocks/CU at the
// (512,4) VGPR cap: 16 waves/CU.
// k-loop keeps the R10 branchy shape (branches bound scheduler hoisting ->
// no spills). Change vs R10: noise prefetch distance 1 -> 2 (3 rotating
// buffers, issued before consumption) so each wave tolerates ~2 iterations
// of HBM latency instead of 1 -> stream should reach BW-bound equilibrium.
__global__ __launch_bounds__(512, 4) void dsnas_kernel(
    const int*   __restrict__ features,   // [COLS, BATCH]
    const float* __restrict__ emb_mean,   // [COLS, NUM_EMB, D]
    const float* __restrict__ emb_std,    // [COLS, NUM_EMB, D]
    const float* __restrict__ W_nc,       // [NPAIRS, 4, 2, D]
    const float* __restrict__ W_cat,      // [NPAIRS, 2, 2*D]
    const float* __restrict__ log_alpha,  // [NPAIRS, 5]
    const float* __restrict__ noise,      // [NPAIRS, 2, BATCH, D]
    float*       __restrict__ out)        // [BATCH, 2]
{
    // Per pair k: 512 floats.
    //  cat (s==4): raw copy of W_cat[k]  -> [a0|b0] at 0..255, [a1|b1] at 256..511
    //  non-cat:    W_nc[k][s] row0 at 0..127, row1 at 256..383 (rest zero, unread)
    __shared__ float wlds[NPAIRS * 512];
    __shared__ int   pos_s[NPAIRS];

    const int tid = threadIdx.x;

    // Hard top-1 routing per pair (argmax over 5, first-max wins)
    if (tid < NPAIRS) {
        const float* la = log_alpha + tid * 5;
        float best = la[0];
        int   bi   = 0;
        #pragma unroll
        for (int t = 1; t < 5; ++t) {
            float v = la[t];
            if (v > best) { best = v; bi = t; }
        }
        pos_s[tid] = bi;
    }
    __syncthreads();

    // ---- Stage selected weights into LDS (512 threads cooperatively) ----
    // 28 pairs * 128 float4 slots = 3584; 7 per thread.
    #pragma unroll
    for (int r = 0; r < 7; ++r) {
        const int idx = tid + r * 512;     // float4 slot id
        const int k   = idx >> 7;          // pair (128 f4 per pair)
        const int f   = idx & 127;         // f4 within pair
        const int row = f >> 5;            // 0..3 (32 f4 per row)
        const int c4  = f & 31;            // f4 within row
        const int s   = pos_s[k];
        floatx4 v = {0.0f, 0.0f, 0.0f, 0.0f};
        if (s == 4) {
            v = ld4(W_cat + (size_t)k * 512 + f * 4);
        } else if ((row & 1) == 0) {
            v = ld4(W_nc + (size_t)(k * 4 + s) * 256 + (row >> 1) * 128 + c4 * 4);
        }
        st4(wlds + k * 512 + f * 4, v);
    }
    __syncthreads();

    const int b    = blockIdx.x * 16 + (tid >> 5); // one batch row per half-wave
    const int lane = tid & 31;
    const int d0   = lane * 4;                     // 4 consecutive dims per lane

    // Per-column mean + 0.01*softplus(std) for this row's 4 dims, in VGPRs.
    floatx4 Mv[COLS], Sv[COLS];
    #pragma unroll
    for (int i = 0; i < COLS; ++i) {
        const int fi = features[i * BATCH + b];
        Mv[i] = ld4(emb_mean + ((size_t)(i * NUM_EMB + fi)) * D + d0);
        const floatx4 s = ld4(emb_std + ((size_t)(i * NUM_EMB + fi)) * D + d0);
        floatx4 sp;
        sp.x = softplus01(s.x);
        sp.y = softplus01(s.y);
        sp.z = softplus01(s.z);
        sp.w = softplus01(s.w);
        Sv[i] = sp;
    }

    constexpr int PI[NPAIRS] = {0,0,0,0,0,0,0, 1,1,1,1,1,1, 2,2,2,2,2, 3,3,3,3, 4,4,4, 5,5, 6};
    constexpr int PJ[NPAIRS] = {1,2,3,4,5,6,7, 2,3,4,5,6,7, 3,4,5,6,7, 4,5,6,7, 5,6,7, 6,7, 7};

    const float* nrow = noise + (size_t)b * D + d0;
    constexpr size_t KSTRIDE = (size_t)2 * BATCH * D;  // between pairs k
    constexpr size_t HSTRIDE = (size_t)BATCH * D;      // between halves

    // Depth-2 prefetch: 3 rotating buffers, k%3 indices (full unroll -> static).
    floatx4 nb0[3], nb1[3];
    nb0[0] = ld4(nrow);
    nb1[0] = ld4(nrow + HSTRIDE);
    nb0[1] = ld4(nrow + KSTRIDE);
    nb1[1] = ld4(nrow + KSTRIDE + HSTRIDE);

    float acc0 = 0.0f, acc1 = 0.0f;

    #pragma unroll
    for (int k = 0; k < NPAIRS; ++k) {
        const int cur = k % 3;
        const int pf  = (k + 2) % 3;

        // Issue pair k+2's noise FIRST (the only VMEM in this loop).
        if (k + 2 < NPAIRS) {
            nb0[pf] = ld4(nrow + (size_t)(k + 2) * KSTRIDE);
            nb1[pf] = ld4(nrow + (size_t)(k + 2) * KSTRIDE + HSTRIDE);
        }

        // Reparameterize (noise issued two iterations ago)
        const int i = PI[k];
        const int j = PJ[k];
        const floatx4 n0 = nb0[cur];
        const floatx4 n1 = nb1[cur];
        const floatx4 p = Mv[i] + Sv[i] * n0;   // Sv pre-scaled by 0.01
        const floatx4 q = Mv[j] + Sv[j] * n1;

        // R10-style wave-uniform branch; weights from LDS only.
        const int    s  = __builtin_amdgcn_readfirstlane(pos_s[k]);
        const float* wk = wlds + k * 512 + d0;

        if (s == 4) {
            const floatx4 A0 = ld4(wk);
            const floatx4 B0 = ld4(wk + 128);
            const floatx4 A1 = ld4(wk + 256);
            const floatx4 B1 = ld4(wk + 384);
            acc0 += dot4(p, A0) + dot4(q, B0);
            acc1 += dot4(p, A1) + dot4(q, B1);
        } else {
            floatx4 c;
            if (s == 0) {
                c = p + q;
            } else if (s == 1) {
                c = p * q;
            } else if (s == 2) {
                c.x = fmaxf(p.x, q.x); c.y = fmaxf(p.y, q.y);
                c.z = fmaxf(p.z, q.z); c.w = fmaxf(p.w, q.w);
            } else {
                c.x = fminf(p.x, q.x); c.y = fminf(p.y, q.y);
                c.z = fminf(p.z, q.z); c.w = fminf(p.w, q.w);
            }
            const floatx4 W0 = ld4(wk);
            const floatx4 W1 = ld4(wk + 256);
            acc0 += dot4(c, W0);
            acc1 += dot4(c, W1);
        }
    }

    // Reduce across the 32 lanes of this half-wave
    #pragma unroll
    for (int m = 16; m >= 1; m >>= 1) {
        acc0 += __shfl_xor(acc0, m, 64);
        acc1 += __shfl_xor(acc1, m, 64);
    }

    if (lane == 0) {
        float2 r; r.x = acc0; r.y = acc1;
        *reinterpret_cast<float2*>(out + b * 2) = r;
    }
}

extern "C" void kernel_launch(void* const* d_in, const int* in_sizes, int n_in,
                              void* d_out, int out_size, void* d_ws, size_t ws_size,
                              hipStream_t stream) {
    const int*   features  = (const int*)  d_in[0];
    const float* emb_mean  = (const float*)d_in[1];
    const float* emb_std   = (const float*)d_in[2];
    const float* W_nc      = (const float*)d_in[3];
    const float* W_cat     = (const float*)d_in[4];
    const float* log_alpha = (const float*)d_in[5];
    const float* noise     = (const float*)d_in[6];
    float*       out       = (float*)d_out;

    dim3 grid(BATCH / 16);  // 512 blocks
    dim3 block(512);        // 8 waves, 16 batch rows/block
    dsnas_kernel<<<grid, block, 0, stream>>>(features, emb_mean, emb_std,
                                             W_nc, W_cat, log_alpha, noise, out);
}